// Round 13
// baseline (461.290 us; speedup 1.0000x reference)
//
#include <hip/hip_runtime.h>
#include <hip/hip_fp16.h>

#define N_NODES 100000
#define N_EDGES 1600000
#define N_GRAPHS 1024
#define DIM_IN 128
#define D1 100
#define D1P 128            // padded p1 row (halves) -> 256 B, 2 aligned cache lines
#define D2 20
#define D2P 32             // padded p2 row (halves) -> 64 B, 1 cache line
#define DIM_SF 32
#define DF1 128
#define DF2 32
#define DOUT 8
#define EPS 1e-5f
#define NPW 8              // nodes per wave in k_agg1
#define DEGCAP 64          // fixed CSR row capacity; P(Pois(16) > 64)*100K ~ 1e-13

typedef _Float16 hh2 __attribute__((ext_vector_type(2)));

// one f32 accumulate of each half in a packed half2, via v_dot2_f32_f16 (exact)
__device__ __forceinline__ void fdacc(unsigned u, float& lo, float& hi) {
  const hh2 MLO = {(_Float16)1.0f, (_Float16)0.0f};
  const hh2 MHI = {(_Float16)0.0f, (_Float16)1.0f};
  hh2 h = __builtin_bit_cast(hh2, u);
  lo = __builtin_amdgcn_fdot2(h, MLO, lo, false);
  hi = __builtin_amdgcn_fdot2(h, MHI, hi, false);
}

__device__ __forceinline__ unsigned pkadd(unsigned a, unsigned b) {
  __half2 x = __builtin_bit_cast(__half2, a);
  __half2 y = __builtin_bit_cast(__half2, b);
  return __builtin_bit_cast(unsigned, __hadd2(x, y));
}

// ---------------- prep: zero per-node cursors + graph offsets ----------------
__global__ void __launch_bounds__(256) k_goff(const int* __restrict__ n2g,
                                              int* __restrict__ g_off,
                                              int* __restrict__ cursor) {
  int i = blockIdx.x * 256 + threadIdx.x;
  if (i < N_NODES) cursor[i] = 0;
  if (i > N_GRAPHS) return;
  if (i == N_GRAPHS) { g_off[i] = N_NODES; return; }
  int lo = 0, hi = N_NODES;
  while (lo < hi) {
    int mid = (lo + hi) >> 1;
    if (n2g[mid] < i) lo = mid + 1; else hi = mid;
  }
  g_off[i] = lo;
}

// ---------------- CSR build in ONE pass: fixed-capacity rows, no sort ----------------
// rank = atomicAdd over 100K spread counters; csr row for node n at [n*DEGCAP, ...).
// cursor[] becomes deg[]. Defensive clamp: drop (impossible) overflow writes.
__global__ void __launch_bounds__(256) k_place(const int* __restrict__ src,
                                               const int* __restrict__ dst,
                                               int* __restrict__ cursor,
                                               int* __restrict__ csr) {
  int e = blockIdx.x * 256 + threadIdx.x;
  if (e >= N_EDGES) return;
  int d = dst[e];
  int r = atomicAdd(&cursor[d], 1);
  if (r < DEGCAP) csr[(size_t)d * DEGCAP + r] = src[e];
}

// ---------------- p1 = fp16(feat @ W1), rows padded to D1P=128 halves ----------------
// 8 nodes x 4 cols per thread; full W1 staged once (51.2 KB).
__global__ void __launch_bounds__(256) k_gemm1(const float* __restrict__ feat,
                                               const float* __restrict__ W1,
                                               __half* __restrict__ p1h) {
  __shared__ float w1s[DIM_IN * D1];   // 51.2 KB
  int t = threadIdx.x;
  for (int i = t; i < DIM_IN * D1; i += 256) w1s[i] = W1[i];
  __syncthreads();
  if (t >= 250) return;
  int q = t % 25, ng = t / 25;         // ng 0..9
  int n0 = blockIdx.x * 80 + ng * 8;   // grid 1250 -> exactly 100000 nodes
  int c0 = q * 4;
  float acc[8][4] = {{0.f}};
  const float* f0 = feat + (size_t)n0 * DIM_IN;
  for (int k = 0; k < DIM_IN; k += 4) {
    float4 w0 = *(const float4*)&w1s[(k + 0) * D1 + c0];
    float4 w1 = *(const float4*)&w1s[(k + 1) * D1 + c0];
    float4 w2 = *(const float4*)&w1s[(k + 2) * D1 + c0];
    float4 w3 = *(const float4*)&w1s[(k + 3) * D1 + c0];
#pragma unroll
    for (int j = 0; j < 8; j++) {
      float4 f = *(const float4*)(f0 + j * DIM_IN + k);
      acc[j][0] += f.x * w0.x + f.y * w1.x + f.z * w2.x + f.w * w3.x;
      acc[j][1] += f.x * w0.y + f.y * w1.y + f.z * w2.y + f.w * w3.y;
      acc[j][2] += f.x * w0.z + f.y * w1.z + f.z * w2.z + f.w * w3.z;
      acc[j][3] += f.x * w0.w + f.y * w1.w + f.z * w2.w + f.w * w3.w;
    }
  }
#pragma unroll
  for (int j = 0; j < 8; j++) {
    __half2* d2 = (__half2*)(p1h + (size_t)(n0 + j) * D1P + c0);
    d2[0] = __floats2half2_rn(acc[j][0], acc[j][1]);
    d2[1] = __floats2half2_rn(acc[j][2], acc[j][3]);
  }
}

// accumulate 8 packed halves into 8 f32 accumulators via fdot2
__device__ __forceinline__ void acc8d(uint4 r, float4& A, float4& B) {
  fdacc(r.x, A.x, A.y);
  fdacc(r.y, A.z, A.w);
  fdacc(r.z, B.x, B.y);
  fdacc(r.w, B.z, B.w);
}

// ---------- agg1: wave-per-node gather, NPW serial nodes per wave, 4 loads in flight ----------
__global__ void __launch_bounds__(256) k_agg1(const __half* __restrict__ p1h,
                                              const int* __restrict__ deg,
                                              const int* __restrict__ csr,
                                              const float* __restrict__ b1,
                                              const float* __restrict__ W2,
                                              __half* __restrict__ p2h) {
  __shared__ float w2s[D1 * D2];
  __shared__ float b1s[D1];
  __shared__ float hbuf[4][104];
  int t = threadIdx.x;
  for (int i = t; i < D1 * D2; i += 256) w2s[i] = W2[i];
  if (t < D1) b1s[t] = b1[t];
  __syncthreads();
  int w = t >> 6, lane = t & 63;
  int g = lane >> 4, o = lane & 15;         // 4 edge-slots x 16B-slots; lane covers ch 8o..8o+7
  const size_t oh = (size_t)(o * 8);        // halves offset within row
  // GEMM2 split: 3 lane-groups of 20 at {0,33,66} -> bank shifts {0,+20,+8}, no 3-way overlap
  int p = lane / 20;                        // 0..3 (p==3 idle)
  int j20 = lane - p * 20;
  int cbeg = (p == 0) ? 0 : (p == 1) ? 33 : 66;
  int cend = (p == 0) ? 33 : (p == 1) ? 66 : 100;
  if (p >= 3) { cbeg = 0; cend = 0; }
  int n0 = (blockIdx.x * 4 + w) * NPW;
  for (int nn = 0; nn < NPW; nn++) {
    int n = n0 + nn;
    int d = deg[n];
    if (d > DEGCAP) d = DEGCAP;             // defensive (cannot happen statistically)
    int ro = n * DEGCAP;                    // fixed-capacity CSR row
    float4 A = {0.f, 0.f, 0.f, 0.f}, B = {0.f, 0.f, 0.f, 0.f};
    if (d > 0) {
      // d <= DEGCAP = 64: single chunk
      int m = d;
      int sv = (lane < m) ? csr[ro + lane] : 0;
      int nr = m >> 2;
      int r = 0;
      for (; r + 3 < nr; r += 4) {          // 16 edges, 4 row-loads in flight
        int sA = __shfl(sv, r * 4 + g);
        int sB = __shfl(sv, r * 4 + 4 + g);
        int sC = __shfl(sv, r * 4 + 8 + g);
        int sD = __shfl(sv, r * 4 + 12 + g);
        uint4 ra = *(const uint4*)(p1h + (size_t)sA * D1P + oh);
        uint4 rb = *(const uint4*)(p1h + (size_t)sB * D1P + oh);
        uint4 rc = *(const uint4*)(p1h + (size_t)sC * D1P + oh);
        uint4 rd = *(const uint4*)(p1h + (size_t)sD * D1P + oh);
        uint4 u, v2;
        u.x = pkadd(ra.x, rb.x); u.y = pkadd(ra.y, rb.y);
        u.z = pkadd(ra.z, rb.z); u.w = pkadd(ra.w, rb.w);
        v2.x = pkadd(rc.x, rd.x); v2.y = pkadd(rc.y, rd.y);
        v2.z = pkadd(rc.z, rd.z); v2.w = pkadd(rc.w, rd.w);
        acc8d(u, A, B);
        acc8d(v2, A, B);
      }
      if (r + 1 < nr) {                     // one leftover pair
        int sA = __shfl(sv, r * 4 + g);
        int sB = __shfl(sv, r * 4 + 4 + g);
        uint4 ra = *(const uint4*)(p1h + (size_t)sA * D1P + oh);
        uint4 rb = *(const uint4*)(p1h + (size_t)sB * D1P + oh);
        uint4 u;
        u.x = pkadd(ra.x, rb.x); u.y = pkadd(ra.y, rb.y);
        u.z = pkadd(ra.z, rb.z); u.w = pkadd(ra.w, rb.w);
        acc8d(u, A, B);
        r += 2;
      }
      if (r < nr) {                         // one leftover quad
        int sA = __shfl(sv, r * 4 + g);
        uint4 ra = *(const uint4*)(p1h + (size_t)sA * D1P + oh);
        acc8d(ra, A, B);
      }
      int rem = m & 3;
      int sT = __shfl(sv, nr * 4 + g);      // hoisted out of divergent branch
      if (rem && g < rem) {
        uint4 ra = *(const uint4*)(p1h + (size_t)sT * D1P + oh);
        acc8d(ra, A, B);
      }
    } else {
      if (g == 0) {                         // deg==0: agg = own p1 row
        uint4 ra = *(const uint4*)(p1h + (size_t)n * D1P + oh);
        acc8d(ra, A, B);
      }
    }
    // reduce the 4 edge-groups: lanes {o, o+16, o+32, o+48} -> lane o
    float v[8] = {A.x, A.y, A.z, A.w, B.x, B.y, B.z, B.w};
#pragma unroll
    for (int j = 0; j < 8; j++) {
      v[j] += __shfl_down(v[j], 32);
      v[j] += __shfl_down(v[j], 16);
    }
    if (lane < 13) {
      float inv = (d > 0) ? 1.0f / (float)d : 1.0f;
#pragma unroll
      for (int j = 0; j < 8; j++) {
        int ch = 8 * lane + j;
        if (ch < D1) hbuf[w][ch] = fmaxf(v[j] * inv + b1s[ch], 0.f);
      }
    }
    // (no __syncthreads: hbuf[w] written and read only by this wave, in order)
    float acc = 0.f;
    for (int c = cbeg; c < cend; c++) acc += hbuf[w][c] * w2s[c * D2 + j20];
    float t1 = __shfl_down(acc, 20);
    float t2 = __shfl_down(acc, 40);
    acc += t1 + t2;
    if (lane < D2)       p2h[(size_t)n * D2P + lane] = __float2half_rn(acc);
    else if (lane < D2P) p2h[(size_t)n * D2P + lane] = __float2half_rn(0.f);
  }
}

// ---------- agg2 + mlp1 fused: block-per-graph gather-pool, then Kronecker+GEMM epilogue ----------
__global__ void __launch_bounds__(512) k_agg2(const __half* __restrict__ p2h,
                                              const int* __restrict__ deg,
                                              const int* __restrict__ csr,
                                              const float* __restrict__ b2,
                                              const int* __restrict__ g_off,
                                              const float* __restrict__ sf,
                                              const float* __restrict__ Wf1,
                                              const float* __restrict__ bf1,
                                              float* __restrict__ y1) {
  __shared__ float ssum[D2];
  __shared__ float b2s[D2];
  __shared__ float hgl[D2], sfl[DIM_SF];
  __shared__ float prod[D2 * DIM_SF];
  __shared__ float red[512];
  int t = threadIdx.x, w = t >> 6, lane = t & 63;
  int g = blockIdx.x;
  if (t < D2) { ssum[t] = 0.f; b2s[t] = b2[t]; }
  if (t < DIM_SF) sfl[t] = sf[g * DIM_SF + t];
  __syncthreads();
  const unsigned* pu = (const unsigned*)p2h;   // 16 dwords per row
  int n_lo = g_off[g], n_hi = g_off[g + 1];
  int nn = n_hi - n_lo;
  int e16 = lane >> 2, o = lane & 3;        // 16 edge-slots x 4 dword-pair slots
  bool xtra = (o == 0);                     // this lane also covers dwords 8,9 (ch 16..19)
  float4 GA = {0.f, 0.f, 0.f, 0.f};
  float4 GX = {0.f, 0.f, 0.f, 0.f};
  for (int n = n_lo + w; n < n_hi; n += 8) {
    int d = deg[n];
    if (d > DEGCAP) d = DEGCAP;             // defensive
    int ro = n * DEGCAP;
    float4 A = {0.f, 0.f, 0.f, 0.f};
    float4 X = {0.f, 0.f, 0.f, 0.f};
    if (d > 0) {
      int m = d;                            // d <= 64: single chunk
      int sv = (lane < m) ? csr[ro + lane] : 0;
      int nr = (m + 15) >> 4;
      for (int r = 0; r < nr; r++) {
        int ei = r * 16 + e16;
        int s0 = __shfl(sv, ei);
        if (ei < m) {
          const unsigned* row = pu + (size_t)s0 * 16;
          uint2 ra = *(const uint2*)(row + 2 * o);
          fdacc(ra.x, A.x, A.y);
          fdacc(ra.y, A.z, A.w);
          if (xtra) {
            uint2 rx = *(const uint2*)(row + 8);
            fdacc(rx.x, X.x, X.y);
            fdacc(rx.y, X.z, X.w);
          }
        }
      }
    } else {
      if (e16 == 0) {                       // deg==0: agg = own p2 row
        const unsigned* row = pu + (size_t)n * 16;
        uint2 ra = *(const uint2*)(row + 2 * o);
        fdacc(ra.x, A.x, A.y);
        fdacc(ra.y, A.z, A.w);
        if (xtra) {
          uint2 rx = *(const uint2*)(row + 8);
          fdacc(rx.x, X.x, X.y);
          fdacc(rx.y, X.z, X.w);
        }
      }
    }
#pragma unroll
    for (int sft = 32; sft >= 4; sft >>= 1) {
      A.x += __shfl_down(A.x, sft); A.y += __shfl_down(A.y, sft);
      A.z += __shfl_down(A.z, sft); A.w += __shfl_down(A.w, sft);
      X.x += __shfl_down(X.x, sft); X.y += __shfl_down(X.y, sft);
      X.z += __shfl_down(X.z, sft); X.w += __shfl_down(X.w, sft);
    }
    float inv = (d > 0) ? 1.0f / (float)d : 1.0f;
    if (lane < 4) {                         // lane == o here
      int ch = 4 * lane;
      GA.x += fmaxf(A.x * inv + b2s[ch + 0], 0.f);
      GA.y += fmaxf(A.y * inv + b2s[ch + 1], 0.f);
      GA.z += fmaxf(A.z * inv + b2s[ch + 2], 0.f);
      GA.w += fmaxf(A.w * inv + b2s[ch + 3], 0.f);
      if (lane == 0) {
        GX.x += fmaxf(X.x * inv + b2s[16], 0.f);
        GX.y += fmaxf(X.y * inv + b2s[17], 0.f);
        GX.z += fmaxf(X.z * inv + b2s[18], 0.f);
        GX.w += fmaxf(X.w * inv + b2s[19], 0.f);
      }
    }
  }
  if (lane < 4) {
    int ch = 4 * lane;
    atomicAdd(&ssum[ch + 0], GA.x);
    atomicAdd(&ssum[ch + 1], GA.y);
    atomicAdd(&ssum[ch + 2], GA.z);
    atomicAdd(&ssum[ch + 3], GA.w);
    if (lane == 0) {
      atomicAdd(&ssum[16], GX.x);
      atomicAdd(&ssum[17], GX.y);
      atomicAdd(&ssum[18], GX.z);
      atomicAdd(&ssum[19], GX.w);
    }
  }
  __syncthreads();
  // ---- mlp1 epilogue: hg = mean, fused = hg (x) sf, y1 = fused @ Wf1 + bf1 ----
  if (t < D2) {
    float inv = (nn > 0) ? 1.0f / (float)nn : 0.f;
    hgl[t] = ssum[t] * inv;
  }
  __syncthreads();
  for (int i = t; i < D2 * DIM_SF; i += 512) prod[i] = hgl[i >> 5] * sfl[i & 31];
  __syncthreads();
  {
    int col = t & 127, qq = t >> 7;         // 4 quarters of 160 over the 640-dot
    float part = 0.f;
    int k0 = qq * 160;
#pragma unroll 4
    for (int k = k0; k < k0 + 160; k++) part += prod[k] * Wf1[k * DF1 + col];
    red[t] = part;
    __syncthreads();
    if (t < DF1)
      y1[g * DF1 + t] = bf1[t] + ((red[t] + red[t + 128]) + (red[t + 256] + red[t + 384]));
  }
}

// ---------- head: bnstats + mlp2 + bnstats + mlp3 (R6-proven) ----------
__global__ void k_bnstats(const float* __restrict__ x, int ld,
                          float* __restrict__ mu, float* __restrict__ rstd) {
  __shared__ float ssum[256], ssq[256];
  int c = blockIdx.x, t = threadIdx.x;
  float s = 0.f, q = 0.f;
  for (int r = t; r < N_GRAPHS; r += 256) { float v = x[r * ld + c]; s += v; q += v * v; }
  ssum[t] = s; ssq[t] = q; __syncthreads();
  for (int off = 128; off > 0; off >>= 1) {
    if (t < off) { ssum[t] += ssum[t + off]; ssq[t] += ssq[t + off]; }
    __syncthreads();
  }
  if (t == 0) {
    float m = ssum[0] / (float)N_GRAPHS;
    float var = ssq[0] / (float)N_GRAPHS - m * m;
    mu[c] = m;
    rstd[c] = rsqrtf(var + EPS);
  }
}

__global__ void k_mlp2(const float* __restrict__ y1, const float* __restrict__ mu1,
                       const float* __restrict__ rstd1, const float* __restrict__ g1,
                       const float* __restrict__ be1, const float* __restrict__ Wf2,
                       const float* __restrict__ bf2, float* __restrict__ y2) {
  int idx = blockIdx.x * 256 + threadIdx.x;
  int g = idx >> 5, o = idx & 31;
  float acc = bf2[o];
  for (int k = 0; k < DF1; k++) {
    float x = (y1[g * DF1 + k] - mu1[k]) * rstd1[k] * g1[k] + be1[k];
    x = fmaxf(x, 0.f);
    acc += x * Wf2[k * DF2 + o];
  }
  y2[g * DF2 + o] = acc;
}

__global__ void k_mlp3(const float* __restrict__ y2, const float* __restrict__ mu2,
                       const float* __restrict__ rstd2, const float* __restrict__ g2,
                       const float* __restrict__ be2, const float* __restrict__ Wf3,
                       const float* __restrict__ bf3, float* __restrict__ out) {
  int idx = blockIdx.x * 256 + threadIdx.x;
  int g = idx >> 3, o = idx & 7;
  float acc = bf3[o];
  for (int k = 0; k < DF2; k++) {
    float x = (y2[g * DF2 + k] - mu2[k]) * rstd2[k] * g2[k] + be2[k];
    x = fmaxf(x, 0.f);
    acc += x * Wf3[k * DOUT + o];
  }
  out[g * DOUT + o] = acc;
}

extern "C" void kernel_launch(void* const* d_in, const int* in_sizes, int n_in,
                              void* d_out, int out_size, void* d_ws, size_t ws_size,
                              hipStream_t stream) {
  const float* feat = (const float*)d_in[0];
  const float* sf   = (const float*)d_in[1];
  const int*   src  = (const int*)d_in[2];
  const int*   dst  = (const int*)d_in[3];
  const int*   n2g  = (const int*)d_in[4];
  const float* W1   = (const float*)d_in[5];
  const float* b1   = (const float*)d_in[6];
  const float* W2   = (const float*)d_in[7];
  const float* b2   = (const float*)d_in[8];
  const float* Wf1  = (const float*)d_in[9];
  const float* bf1  = (const float*)d_in[10];
  const float* g1   = (const float*)d_in[11];
  const float* be1  = (const float*)d_in[12];
  const float* Wf2  = (const float*)d_in[13];
  const float* bf2  = (const float*)d_in[14];
  const float* g2   = (const float*)d_in[15];
  const float* be2  = (const float*)d_in[16];
  const float* Wf3  = (const float*)d_in[17];
  const float* bf3  = (const float*)d_in[18];
  float* out = (float*)d_out;

  char* ws = (char*)d_ws;
  size_t off = 0;
  auto alloc = [&](size_t bytes) -> void* {
    void* p = ws + off;
    off = (off + bytes + 255) & ~(size_t)255;
    return p;
  };
  int*      cursor   = (int*)alloc(N_NODES * 4);      // zeroed by k_goff; becomes deg[]
  int*      g_offs   = (int*)alloc((N_GRAPHS + 1) * 4);
  int*      csr      = (int*)alloc((size_t)N_NODES * DEGCAP * 4);   // 25.6 MB
  __half*   p1h      = (__half*)alloc((size_t)N_NODES * D1P * 2);
  __half*   p2h      = (__half*)alloc((size_t)N_NODES * D2P * 2);
  float*    y1       = (float*)alloc((size_t)N_GRAPHS * DF1 * 4);
  float*    y2       = (float*)alloc((size_t)N_GRAPHS * DF2 * 4);
  float*    mu1      = (float*)alloc(DF1 * 4);
  float*    rstd1    = (float*)alloc(DF1 * 4);
  float*    mu2      = (float*)alloc(DF2 * 4);
  float*    rstd2    = (float*)alloc(DF2 * 4);

  k_goff<<<(N_NODES + 255) / 256, 256, 0, stream>>>(n2g, g_offs, cursor);
  k_place<<<(N_EDGES + 255) / 256, 256, 0, stream>>>(src, dst, cursor, csr);
  k_gemm1<<<N_NODES / 80, 256, 0, stream>>>(feat, W1, p1h);
  k_agg1<<<N_NODES / (4 * NPW), 256, 0, stream>>>(p1h, cursor, csr, b1, W2, p2h);
  k_agg2<<<N_GRAPHS, 512, 0, stream>>>(p2h, cursor, csr, b2, g_offs,
                                       sf, Wf1, bf1, y1);
  k_bnstats<<<DF1, 256, 0, stream>>>(y1, DF1, mu1, rstd1);
  k_mlp2<<<(N_GRAPHS * DF2) / 256, 256, 0, stream>>>(y1, mu1, rstd1, g1, be1, Wf2, bf2, y2);
  k_bnstats<<<DF2, 256, 0, stream>>>(y2, DF2, mu2, rstd2);
  k_mlp3<<<(N_GRAPHS * DOUT) / 256, 256, 0, stream>>>(y2, mu2, rstd2, g2, be2, Wf3, bf3, out);
}

// Round 14
// 367.918 us; speedup vs baseline: 1.2538x; 1.2538x over previous
//
#include <hip/hip_runtime.h>
#include <hip/hip_fp16.h>

#define N_NODES 100000
#define N_EDGES 1600000
#define N_GRAPHS 1024
#define DIM_IN 128
#define D1 100
#define D1P 128            // padded p1 row (halves) -> 256 B, 2 aligned cache lines
#define D2 20
#define D2P 32             // padded p2 row (halves) -> 64 B, 1 cache line
#define DIM_SF 32
#define DF1 128
#define DF2 32
#define DOUT 8
#define EPS 1e-5f
#define NPW 8              // nodes per wave in k_agg1

typedef _Float16 hh2 __attribute__((ext_vector_type(2)));

// one f32 accumulate of each half in a packed half2, via v_dot2_f32_f16 (exact)
__device__ __forceinline__ void fdacc(unsigned u, float& lo, float& hi) {
  const hh2 MLO = {(_Float16)1.0f, (_Float16)0.0f};
  const hh2 MHI = {(_Float16)0.0f, (_Float16)1.0f};
  hh2 h = __builtin_bit_cast(hh2, u);
  lo = __builtin_amdgcn_fdot2(h, MLO, lo, false);
  hi = __builtin_amdgcn_fdot2(h, MHI, hi, false);
}

__device__ __forceinline__ unsigned pkadd(unsigned a, unsigned b) {
  __half2 x = __builtin_bit_cast(__half2, a);
  __half2 y = __builtin_bit_cast(__half2, b);
  return __builtin_bit_cast(unsigned, __hadd2(x, y));
}

// ---------------- bucket-sort CSR build (static-capacity buckets) ----------------
#define NBK 512                 // buckets
#define BW 196                  // nodes per bucket (512*196 = 100352 >= N_NODES)
#define BKCAP 4096              // bucket capacity (max load ~3400)
#define EPB 4096                // edges per scatter block (R9-proven: fewer blocks, amortized scan)
#define NBLK1 ((N_EDGES + EPB - 1) / EPB)   // 391
#define GEMM1_NB (N_NODES / 80) // 1250

// ---------------- prep: graph offsets + zero bucket counters ----------------
__global__ void __launch_bounds__(256) k_goff(const int* __restrict__ n2g,
                                              int* __restrict__ g_off,
                                              int* __restrict__ bucket_cnt) {
  int g = blockIdx.x * 256 + threadIdx.x;
  if (g < NBK) bucket_cnt[g] = 0;
  if (g > N_GRAPHS) return;
  if (g == N_GRAPHS) { g_off[g] = N_NODES; return; }
  int lo = 0, hi = N_NODES;
  while (lo < hi) {
    int mid = (lo + hi) >> 1;
    if (n2g[mid] < g) lo = mid + 1; else hi = mid;
  }
  g_off[g] = lo;
}

// ---------------- fused: edge bucket-scatter (blocks 0..NBLK1-1)  ----------------
// ----------------        + p1 = fp16(feat @ W1) (blocks NBLK1..) ----------------
// R9-proven form: union LDS = 31 KB (scatter EPB=4096: tables + sval 16KB + ushort sbkt 8KB;
// gemm: W1 staged in two 64-row passes of 25.6 KB). Measured 91-93 us.
__global__ void __launch_bounds__(256) k_sc_gemm(const int* __restrict__ src,
                                                 const int* __restrict__ dst,
                                                 int* __restrict__ bucket_cnt,
                                                 unsigned* __restrict__ packed_out,
                                                 const float* __restrict__ feat,
                                                 const float* __restrict__ W1,
                                                 __half* __restrict__ p1h) {
  __shared__ __align__(16) char smem[31744];
  int t = threadIdx.x;
  if (blockIdx.x < NBLK1) {
    // ---- bucket scatter (staged, bucket-major; coalesced write-out) ----
    int* hist   = (int*)smem;                       // 2048 B
    int* lbase  = (int*)(smem + 2048);              // 2048 B
    int* gbase  = (int*)(smem + 4096);              // 2048 B
    int* ssum   = (int*)(smem + 6144);              // 1024 B
    unsigned* sval = (unsigned*)(smem + 7168);      // 16384 B
    unsigned short* sbkt = (unsigned short*)(smem + 23552);  // 8192 B
    int blk = blockIdx.x;
    for (int i = t; i < NBK; i += 256) hist[i] = 0;
    __syncthreads();
    int base = blk * EPB;
    unsigned pk[16]; int bn[16]; int rk[16];
#pragma unroll
    for (int r = 0; r < 16; r++) {
      int e = base + r * 256 + t;
      bn[r] = -1;
      if (e < N_EDGES) {
        int dv = dst[e];
        unsigned b = (unsigned)dv / BW;
        unsigned ld = (unsigned)dv - b * BW;
        bn[r] = (int)b;
        pk[r] = ((unsigned)src[e] << 8) | ld;
        rk[r] = atomicAdd(&hist[b], 1);
      }
    }
    __syncthreads();
    // exclusive scan of hist[512] with 256 threads (2 bins each)
    int h0 = hist[2 * t], h1 = hist[2 * t + 1];
    int s = h0 + h1;
    ssum[t] = s; __syncthreads();
    for (int off = 1; off < 256; off <<= 1) {
      int x = (t >= off) ? ssum[t - off] : 0;
      __syncthreads();
      ssum[t] += x;
      __syncthreads();
    }
    int excl = ssum[t] - s;
    lbase[2 * t] = excl;
    lbase[2 * t + 1] = excl + h0;
    gbase[2 * t]     = (h0 > 0) ? (2 * t) * BKCAP     + atomicAdd(&bucket_cnt[2 * t],     h0) : 0;
    gbase[2 * t + 1] = (h1 > 0) ? (2 * t + 1) * BKCAP + atomicAdd(&bucket_cnt[2 * t + 1], h1) : 0;
    __syncthreads();
#pragma unroll
    for (int r = 0; r < 16; r++) {
      if (bn[r] >= 0) {
        int li = lbase[bn[r]] + rk[r];
        sval[li] = pk[r];
        sbkt[li] = (unsigned short)bn[r];
      }
    }
    __syncthreads();
    int cnt = N_EDGES - base; if (cnt > EPB) cnt = EPB;
    for (int i = t; i < cnt; i += 256) {
      int b = sbkt[i];
      packed_out[gbase[b] + (i - lbase[b])] = sval[i];   // == gbase[b] + rk
    }
  } else {
    // ---- gemm1: 8 nodes x 4 cols per thread; W1 staged in two 64-row passes ----
    float* w1s = (float*)smem;                      // 64*100 floats = 25.6 KB
    bool act = (t < 250);
    int q = t % 25, ng = t / 25;                    // ng 0..9
    int n0 = (int)(blockIdx.x - NBLK1) * 80 + ng * 8;
    int c0 = q * 4;
    float acc[8][4] = {{0.f}};
    const float* f0 = feat + (size_t)n0 * DIM_IN;
    for (int pass = 0; pass < 2; pass++) {
      __syncthreads();
      for (int i = t; i < 64 * D1; i += 256) w1s[i] = W1[pass * 64 * D1 + i];
      __syncthreads();
      if (act) {
        int kg0 = pass * 64;
        for (int k = 0; k < 64; k += 4) {
          float4 w0 = *(const float4*)&w1s[(k + 0) * D1 + c0];
          float4 w1 = *(const float4*)&w1s[(k + 1) * D1 + c0];
          float4 w2 = *(const float4*)&w1s[(k + 2) * D1 + c0];
          float4 w3 = *(const float4*)&w1s[(k + 3) * D1 + c0];
#pragma unroll
          for (int j = 0; j < 8; j++) {
            float4 f = *(const float4*)(f0 + j * DIM_IN + kg0 + k);
            acc[j][0] += f.x * w0.x + f.y * w1.x + f.z * w2.x + f.w * w3.x;
            acc[j][1] += f.x * w0.y + f.y * w1.y + f.z * w2.y + f.w * w3.y;
            acc[j][2] += f.x * w0.z + f.y * w1.z + f.z * w2.z + f.w * w3.z;
            acc[j][3] += f.x * w0.w + f.y * w1.w + f.z * w2.w + f.w * w3.w;
          }
        }
      }
    }
    if (act) {
#pragma unroll
      for (int j = 0; j < 8; j++) {
        __half2* d2 = (__half2*)(p1h + (size_t)(n0 + j) * D1P + c0);
        d2[0] = __floats2half2_rn(acc[j][0], acc[j][1]);
        d2[1] = __floats2half2_rn(acc[j][2], acc[j][3]);
      }
    }
  }
}

// pass 2: one block per bucket. Sort within bucket in LDS, emit exact CSR.
__global__ void __launch_bounds__(256) k_bfine(const unsigned* __restrict__ packed_in,
                                               const int* __restrict__ bucket_cnt,
                                               int* __restrict__ csr,
                                               int* __restrict__ deg,
                                               int* __restrict__ row_off) {
  __shared__ unsigned sval[BKCAP];   // 16 KB
  __shared__ int scsr[BKCAP];        // 16 KB
  __shared__ int hist[256];
  __shared__ int soff[256];
  __shared__ int cur[256];
  int b = blockIdx.x, t = threadIdx.x;
  int start = b * BKCAP;
  int cnt = bucket_cnt[b];
  if (cnt > BKCAP) cnt = BKCAP;
  hist[t] = 0;
  __syncthreads();
  for (int i = t; i < cnt; i += 256) {
    unsigned v = packed_in[start + i];
    sval[i] = v;
    atomicAdd(&hist[v & 255u], 1);
  }
  __syncthreads();
  int h = hist[t];
  soff[t] = h; __syncthreads();
  for (int off = 1; off < 256; off <<= 1) {
    int x = (t >= off) ? soff[t - off] : 0;
    __syncthreads();
    soff[t] += x;
    __syncthreads();
  }
  int excl = soff[t] - h;
  cur[t] = excl;
  int n = b * BW + t;
  if (t < BW && n < N_NODES) { deg[n] = h; row_off[n] = start + excl; }
  __syncthreads();
  for (int i = t; i < cnt; i += 256) {
    unsigned v = sval[i];
    int pos = atomicAdd(&cur[v & 255u], 1);
    scsr[pos] = (int)(v >> 8);
  }
  __syncthreads();
  for (int i = t; i < cnt; i += 256) csr[start + i] = scsr[i];
}

// accumulate 8 packed halves into 8 f32 accumulators via fdot2
__device__ __forceinline__ void acc8d(uint4 r, float4& A, float4& B) {
  fdacc(r.x, A.x, A.y);
  fdacc(r.y, A.z, A.w);
  fdacc(r.z, B.x, B.y);
  fdacc(r.w, B.z, B.w);
}

// ---------- agg1: wave-per-node gather, NPW serial nodes per wave, 4 loads in flight ----------
__global__ void __launch_bounds__(256) k_agg1(const __half* __restrict__ p1h,
                                              const int* __restrict__ deg,
                                              const int* __restrict__ row_off,
                                              const int* __restrict__ csr,
                                              const float* __restrict__ b1,
                                              const float* __restrict__ W2,
                                              __half* __restrict__ p2h) {
  __shared__ float w2s[D1 * D2];
  __shared__ float b1s[D1];
  __shared__ float hbuf[4][104];
  int t = threadIdx.x;
  for (int i = t; i < D1 * D2; i += 256) w2s[i] = W2[i];
  if (t < D1) b1s[t] = b1[t];
  __syncthreads();
  int w = t >> 6, lane = t & 63;
  int g = lane >> 4, o = lane & 15;         // 4 edge-slots x 16B-slots; lane covers ch 8o..8o+7
  const size_t oh = (size_t)(o * 8);        // halves offset within row
  // GEMM2 split: 3 lane-groups of 20 at {0,33,66} -> bank shifts {0,+20,+8}, no 3-way overlap
  int p = lane / 20;                        // 0..3 (p==3 idle)
  int j20 = lane - p * 20;
  int cbeg = (p == 0) ? 0 : (p == 1) ? 33 : 66;
  int cend = (p == 0) ? 33 : (p == 1) ? 66 : 100;
  if (p >= 3) { cbeg = 0; cend = 0; }
  int n0 = (blockIdx.x * 4 + w) * NPW;
  for (int nn = 0; nn < NPW; nn++) {
    int n = n0 + nn;
    int d = deg[n], ro = row_off[n];
    float4 A = {0.f, 0.f, 0.f, 0.f}, B = {0.f, 0.f, 0.f, 0.f};
    if (d > 0) {
      for (int base = 0; base < d; base += 64) {
        int m = d - base; if (m > 64) m = 64;
        int sv = (lane < m) ? csr[ro + base + lane] : 0;
        int nr = m >> 2;
        int r = 0;
        for (; r + 3 < nr; r += 4) {        // 16 edges, 4 row-loads in flight
          int sA = __shfl(sv, r * 4 + g);
          int sB = __shfl(sv, r * 4 + 4 + g);
          int sC = __shfl(sv, r * 4 + 8 + g);
          int sD = __shfl(sv, r * 4 + 12 + g);
          uint4 ra = *(const uint4*)(p1h + (size_t)sA * D1P + oh);
          uint4 rb = *(const uint4*)(p1h + (size_t)sB * D1P + oh);
          uint4 rc = *(const uint4*)(p1h + (size_t)sC * D1P + oh);
          uint4 rd = *(const uint4*)(p1h + (size_t)sD * D1P + oh);
          uint4 u, v2;
          u.x = pkadd(ra.x, rb.x); u.y = pkadd(ra.y, rb.y);
          u.z = pkadd(ra.z, rb.z); u.w = pkadd(ra.w, rb.w);
          v2.x = pkadd(rc.x, rd.x); v2.y = pkadd(rc.y, rd.y);
          v2.z = pkadd(rc.z, rd.z); v2.w = pkadd(rc.w, rd.w);
          acc8d(u, A, B);
          acc8d(v2, A, B);
        }
        if (r + 1 < nr) {                   // one leftover pair
          int sA = __shfl(sv, r * 4 + g);
          int sB = __shfl(sv, r * 4 + 4 + g);
          uint4 ra = *(const uint4*)(p1h + (size_t)sA * D1P + oh);
          uint4 rb = *(const uint4*)(p1h + (size_t)sB * D1P + oh);
          uint4 u;
          u.x = pkadd(ra.x, rb.x); u.y = pkadd(ra.y, rb.y);
          u.z = pkadd(ra.z, rb.z); u.w = pkadd(ra.w, rb.w);
          acc8d(u, A, B);
          r += 2;
        }
        if (r < nr) {                       // one leftover quad
          int sA = __shfl(sv, r * 4 + g);
          uint4 ra = *(const uint4*)(p1h + (size_t)sA * D1P + oh);
          acc8d(ra, A, B);
        }
        int rem = m & 3;
        int sT = __shfl(sv, nr * 4 + g);    // hoisted out of divergent branch
        if (rem && g < rem) {
          uint4 ra = *(const uint4*)(p1h + (size_t)sT * D1P + oh);
          acc8d(ra, A, B);
        }
      }
    } else {
      if (g == 0) {                         // deg==0: agg = own p1 row
        uint4 ra = *(const uint4*)(p1h + (size_t)n * D1P + oh);
        acc8d(ra, A, B);
      }
    }
    // reduce the 4 edge-groups: lanes {o, o+16, o+32, o+48} -> lane o
    float v[8] = {A.x, A.y, A.z, A.w, B.x, B.y, B.z, B.w};
#pragma unroll
    for (int j = 0; j < 8; j++) {
      v[j] += __shfl_down(v[j], 32);
      v[j] += __shfl_down(v[j], 16);
    }
    if (lane < 13) {
      float inv = (d > 0) ? 1.0f / (float)d : 1.0f;
#pragma unroll
      for (int j = 0; j < 8; j++) {
        int ch = 8 * lane + j;
        if (ch < D1) hbuf[w][ch] = fmaxf(v[j] * inv + b1s[ch], 0.f);
      }
    }
    // (no __syncthreads: hbuf[w] written and read only by this wave, in order)
    float acc = 0.f;
    for (int c = cbeg; c < cend; c++) acc += hbuf[w][c] * w2s[c * D2 + j20];
    float t1 = __shfl_down(acc, 20);
    float t2 = __shfl_down(acc, 40);
    acc += t1 + t2;
    if (lane < D2)       p2h[(size_t)n * D2P + lane] = __float2half_rn(acc);
    else if (lane < D2P) p2h[(size_t)n * D2P + lane] = __float2half_rn(0.f);
  }
}

// ---------- agg2 + mlp1 fused: block-per-graph gather-pool, then Kronecker+GEMM epilogue ----------
__global__ void __launch_bounds__(512) k_agg2(const __half* __restrict__ p2h,
                                              const int* __restrict__ deg,
                                              const int* __restrict__ row_off,
                                              const int* __restrict__ csr,
                                              const float* __restrict__ b2,
                                              const int* __restrict__ g_off,
                                              const float* __restrict__ sf,
                                              const float* __restrict__ Wf1,
                                              const float* __restrict__ bf1,
                                              float* __restrict__ y1) {
  __shared__ float ssum[D2];
  __shared__ float b2s[D2];
  __shared__ float hgl[D2], sfl[DIM_SF];
  __shared__ float prod[D2 * DIM_SF];
  __shared__ float red[512];
  int t = threadIdx.x, w = t >> 6, lane = t & 63;
  int g = blockIdx.x;
  if (t < D2) { ssum[t] = 0.f; b2s[t] = b2[t]; }
  if (t < DIM_SF) sfl[t] = sf[g * DIM_SF + t];
  __syncthreads();
  const unsigned* pu = (const unsigned*)p2h;   // 16 dwords per row
  int n_lo = g_off[g], n_hi = g_off[g + 1];
  int nn = n_hi - n_lo;
  int e16 = lane >> 2, o = lane & 3;        // 16 edge-slots x 4 dword-pair slots
  bool xtra = (o == 0);                     // this lane also covers dwords 8,9 (ch 16..19)
  float4 GA = {0.f, 0.f, 0.f, 0.f};
  float4 GX = {0.f, 0.f, 0.f, 0.f};
  for (int n = n_lo + w; n < n_hi; n += 8) {
    int d = deg[n], ro = row_off[n];
    float4 A = {0.f, 0.f, 0.f, 0.f};
    float4 X = {0.f, 0.f, 0.f, 0.f};
    if (d > 0) {
      for (int base = 0; base < d; base += 64) {
        int m = d - base; if (m > 64) m = 64;
        int sv = (lane < m) ? csr[ro + base + lane] : 0;
        int nr = (m + 15) >> 4;
        for (int r = 0; r < nr; r++) {
          int ei = r * 16 + e16;
          int s0 = __shfl(sv, ei);
          if (ei < m) {
            const unsigned* row = pu + (size_t)s0 * 16;
            uint2 ra = *(const uint2*)(row + 2 * o);
            fdacc(ra.x, A.x, A.y);
            fdacc(ra.y, A.z, A.w);
            if (xtra) {
              uint2 rx = *(const uint2*)(row + 8);
              fdacc(rx.x, X.x, X.y);
              fdacc(rx.y, X.z, X.w);
            }
          }
        }
      }
    } else {
      if (e16 == 0) {                       // deg==0: agg = own p2 row
        const unsigned* row = pu + (size_t)n * 16;
        uint2 ra = *(const uint2*)(row + 2 * o);
        fdacc(ra.x, A.x, A.y);
        fdacc(ra.y, A.z, A.w);
        if (xtra) {
          uint2 rx = *(const uint2*)(row + 8);
          fdacc(rx.x, X.x, X.y);
          fdacc(rx.y, X.z, X.w);
        }
      }
    }
#pragma unroll
    for (int sft = 32; sft >= 4; sft >>= 1) {
      A.x += __shfl_down(A.x, sft); A.y += __shfl_down(A.y, sft);
      A.z += __shfl_down(A.z, sft); A.w += __shfl_down(A.w, sft);
      X.x += __shfl_down(X.x, sft); X.y += __shfl_down(X.y, sft);
      X.z += __shfl_down(X.z, sft); X.w += __shfl_down(X.w, sft);
    }
    float inv = (d > 0) ? 1.0f / (float)d : 1.0f;
    if (lane < 4) {                         // lane == o here
      int ch = 4 * lane;
      GA.x += fmaxf(A.x * inv + b2s[ch + 0], 0.f);
      GA.y += fmaxf(A.y * inv + b2s[ch + 1], 0.f);
      GA.z += fmaxf(A.z * inv + b2s[ch + 2], 0.f);
      GA.w += fmaxf(A.w * inv + b2s[ch + 3], 0.f);
      if (lane == 0) {
        GX.x += fmaxf(X.x * inv + b2s[16], 0.f);
        GX.y += fmaxf(X.y * inv + b2s[17], 0.f);
        GX.z += fmaxf(X.z * inv + b2s[18], 0.f);
        GX.w += fmaxf(X.w * inv + b2s[19], 0.f);
      }
    }
  }
  if (lane < 4) {
    int ch = 4 * lane;
    atomicAdd(&ssum[ch + 0], GA.x);
    atomicAdd(&ssum[ch + 1], GA.y);
    atomicAdd(&ssum[ch + 2], GA.z);
    atomicAdd(&ssum[ch + 3], GA.w);
    if (lane == 0) {
      atomicAdd(&ssum[16], GX.x);
      atomicAdd(&ssum[17], GX.y);
      atomicAdd(&ssum[18], GX.z);
      atomicAdd(&ssum[19], GX.w);
    }
  }
  __syncthreads();
  // ---- mlp1 epilogue: hg = mean, fused = hg (x) sf, y1 = fused @ Wf1 + bf1 ----
  if (t < D2) {
    float inv = (nn > 0) ? 1.0f / (float)nn : 0.f;
    hgl[t] = ssum[t] * inv;
  }
  __syncthreads();
  for (int i = t; i < D2 * DIM_SF; i += 512) prod[i] = hgl[i >> 5] * sfl[i & 31];
  __syncthreads();
  {
    int col = t & 127, qq = t >> 7;         // 4 quarters of 160 over the 640-dot
    float part = 0.f;
    int k0 = qq * 160;
#pragma unroll 4
    for (int k = k0; k < k0 + 160; k++) part += prod[k] * Wf1[k * DF1 + col];
    red[t] = part;
    __syncthreads();
    if (t < DF1)
      y1[g * DF1 + t] = bf1[t] + ((red[t] + red[t + 128]) + (red[t + 256] + red[t + 384]));
  }
}

// ---------- head: bnstats + mlp2 + bnstats + mlp3 (R6-proven) ----------
__global__ void k_bnstats(const float* __restrict__ x, int ld,
                          float* __restrict__ mu, float* __restrict__ rstd) {
  __shared__ float ssum[256], ssq[256];
  int c = blockIdx.x, t = threadIdx.x;
  float s = 0.f, q = 0.f;
  for (int r = t; r < N_GRAPHS; r += 256) { float v = x[r * ld + c]; s += v; q += v * v; }
  ssum[t] = s; ssq[t] = q; __syncthreads();
  for (int off = 128; off > 0; off >>= 1) {
    if (t < off) { ssum[t] += ssum[t + off]; ssq[t] += ssq[t + off]; }
    __syncthreads();
  }
  if (t == 0) {
    float m = ssum[0] / (float)N_GRAPHS;
    float var = ssq[0] / (float)N_GRAPHS - m * m;
    mu[c] = m;
    rstd[c] = rsqrtf(var + EPS);
  }
}

__global__ void k_mlp2(const float* __restrict__ y1, const float* __restrict__ mu1,
                       const float* __restrict__ rstd1, const float* __restrict__ g1,
                       const float* __restrict__ be1, const float* __restrict__ Wf2,
                       const float* __restrict__ bf2, float* __restrict__ y2) {
  int idx = blockIdx.x * 256 + threadIdx.x;
  int g = idx >> 5, o = idx & 31;
  float acc = bf2[o];
  for (int k = 0; k < DF1; k++) {
    float x = (y1[g * DF1 + k] - mu1[k]) * rstd1[k] * g1[k] + be1[k];
    x = fmaxf(x, 0.f);
    acc += x * Wf2[k * DF2 + o];
  }
  y2[g * DF2 + o] = acc;
}

__global__ void k_mlp3(const float* __restrict__ y2, const float* __restrict__ mu2,
                       const float* __restrict__ rstd2, const float* __restrict__ g2,
                       const float* __restrict__ be2, const float* __restrict__ Wf3,
                       const float* __restrict__ bf3, float* __restrict__ out) {
  int idx = blockIdx.x * 256 + threadIdx.x;
  int g = idx >> 3, o = idx & 7;
  float acc = bf3[o];
  for (int k = 0; k < DF2; k++) {
    float x = (y2[g * DF2 + k] - mu2[k]) * rstd2[k] * g2[k] + be2[k];
    x = fmaxf(x, 0.f);
    acc += x * Wf3[k * DOUT + o];
  }
  out[g * DOUT + o] = acc;
}

extern "C" void kernel_launch(void* const* d_in, const int* in_sizes, int n_in,
                              void* d_out, int out_size, void* d_ws, size_t ws_size,
                              hipStream_t stream) {
  const float* feat = (const float*)d_in[0];
  const float* sf   = (const float*)d_in[1];
  const int*   src  = (const int*)d_in[2];
  const int*   dst  = (const int*)d_in[3];
  const int*   n2g  = (const int*)d_in[4];
  const float* W1   = (const float*)d_in[5];
  const float* b1   = (const float*)d_in[6];
  const float* W2   = (const float*)d_in[7];
  const float* b2   = (const float*)d_in[8];
  const float* Wf1  = (const float*)d_in[9];
  const float* bf1  = (const float*)d_in[10];
  const float* g1   = (const float*)d_in[11];
  const float* be1  = (const float*)d_in[12];
  const float* Wf2  = (const float*)d_in[13];
  const float* bf2  = (const float*)d_in[14];
  const float* g2   = (const float*)d_in[15];
  const float* be2  = (const float*)d_in[16];
  const float* Wf3  = (const float*)d_in[17];
  const float* bf3  = (const float*)d_in[18];
  float* out = (float*)d_out;

  char* ws = (char*)d_ws;
  size_t off = 0;
  auto alloc = [&](size_t bytes) -> void* {
    void* p = ws + off;
    off = (off + bytes + 255) & ~(size_t)255;
    return p;
  };
  int*      bucket_cnt = (int*)alloc(NBK * 4);
  int*      g_offs   = (int*)alloc((N_GRAPHS + 1) * 4);
  int*      deg      = (int*)alloc(N_NODES * 4);
  int*      row_off  = (int*)alloc(N_NODES * 4);
  unsigned* packed   = (unsigned*)alloc((size_t)NBK * BKCAP * 4);
  int*      csr      = (int*)alloc((size_t)NBK * BKCAP * 4);
  __half*   p1h      = (__half*)alloc((size_t)N_NODES * D1P * 2);
  __half*   p2h      = (__half*)alloc((size_t)N_NODES * D2P * 2);
  float*    y1       = (float*)alloc((size_t)N_GRAPHS * DF1 * 4);
  float*    y2       = (float*)alloc((size_t)N_GRAPHS * DF2 * 4);
  float*    mu1      = (float*)alloc(DF1 * 4);
  float*    rstd1    = (float*)alloc(DF1 * 4);
  float*    mu2      = (float*)alloc(DF2 * 4);
  float*    rstd2    = (float*)alloc(DF2 * 4);

  k_goff<<<(N_GRAPHS + 1 + 255) / 256, 256, 0, stream>>>(n2g, g_offs, bucket_cnt);
  k_sc_gemm<<<NBLK1 + GEMM1_NB, 256, 0, stream>>>(src, dst, bucket_cnt, packed,
                                                  feat, W1, p1h);
  k_bfine<<<NBK, 256, 0, stream>>>(packed, bucket_cnt, csr, deg, row_off);
  k_agg1<<<N_NODES / (4 * NPW), 256, 0, stream>>>(p1h, deg, row_off, csr, b1, W2, p2h);
  k_agg2<<<N_GRAPHS, 512, 0, stream>>>(p2h, deg, row_off, csr, b2, g_offs,
                                       sf, Wf1, bf1, y1);
  k_bnstats<<<DF1, 256, 0, stream>>>(y1, DF1, mu1, rstd1);
  k_mlp2<<<(N_GRAPHS * DF2) / 256, 256, 0, stream>>>(y1, mu1, rstd1, g1, be1, Wf2, bf2, y2);
  k_bnstats<<<DF2, 256, 0, stream>>>(y2, DF2, mu2, rstd2);
  k_mlp3<<<(N_GRAPHS * DOUT) / 256, 256, 0, stream>>>(y2, mu2, rstd2, g2, be2, Wf3, bf3, out);
}